// Round 12
// baseline (423.773 us; speedup 1.0000x reference)
//
#include <hip/hip_runtime.h>
#include <math.h>

#define LPTS 257

// ===========================================================================
// XLA-CPU float32 emulation (round 12 = round 9 config + SATURATING CAST):
//   exp  : Eigen pexp (fmaf)                 [r9 cell; expf regressed in r10]
//   erf  : XLA alpha/beta rational, fmaf     [r9 cell; plain regressed in r8]
//   einsum: fused fmaf chain                 [r9 cell; plain regressed in r11]
//   t    : f64 linspace/255 rounded to f32   [r9 cell]
//   cast : XLA float->int16 SATURATES (min(r,32767)); int16 ADD wraps.
//          This is the decoded source of r9's residual absmax=14976:
//          ref(r>32767) = l-32769 vs mine r+l-65536 -> bf16 diff 14976.
// ===========================================================================

__device__ __forceinline__ float xla_exp32(float x)
{
#pragma clang fp contract(off)
    x = fminf(x, 88.3762626647950f);
    x = fmaxf(x, -87.3365478515625f);
    const float m = floorf(fmaf(x, 1.44269504088896341f, 0.5f));
    float r = fmaf(m, -0.693359375f, x);
    r = fmaf(m, 2.12194440e-4f, r);
    const float r2 = r * r;
    float p = 1.9875691500e-4f;
    p = fmaf(p, r, 1.3981999507e-3f);
    p = fmaf(p, r, 8.3334519073e-3f);
    p = fmaf(p, r, 4.1665795894e-2f);
    p = fmaf(p, r, 1.6666665459e-1f);
    p = fmaf(p, r, 5.0000001201e-1f);
    float y = fmaf(p, r2, r) + 1.0f;
    const int e = (int)m;
    const float s = __int_as_float((e + 127) << 23);   // 2^m
    return y * s;
}

__device__ __forceinline__ float xla_erf32(float x)
{
#pragma clang fp contract(off)
    x = fminf(fmaxf(x, -4.0f), 4.0f);
    const float x2 = x * x;
    float pa = -2.72614225801306e-10f;
    pa = fmaf(pa, x2, 2.77068142495902e-08f);
    pa = fmaf(pa, x2, -2.10102402082508e-06f);
    pa = fmaf(pa, x2, -5.69250639462346e-05f);
    pa = fmaf(pa, x2, -7.34990630326855e-04f);
    pa = fmaf(pa, x2, -2.95459980854025e-03f);
    pa = fmaf(pa, x2, -1.60960333262415e-02f);
    float pb = -1.45660718464996e-05f;
    pb = fmaf(pb, x2, -2.13374055278905e-04f);
    pb = fmaf(pb, x2, -1.68282697438203e-03f);
    pb = fmaf(pb, x2, -7.37332916720468e-03f);
    pb = fmaf(pb, x2, -1.42647390514189e-02f);
    return x * pa / pb;
}

// erfc core for x >= 1 (outside this input's reachable range; kept for safety)
__device__ __forceinline__ float xla_erfc_ge1(float x)
{
#pragma clang fp contract(off)
    const float z = xla_exp32(-(x * x));
    const float q = 1.0f / x;
    const float y2 = q * q;
    float p;
    if (x < 2.0f) {
        p = 2.326819970068386e-02f;
        p = fmaf(p, y2, -1.387039388740657e-01f);
        p = fmaf(p, y2, 3.687424674597105e-01f);
        p = fmaf(p, y2, -5.824733027278666e-01f);
        p = fmaf(p, y2, 6.210004621745983e-01f);
        p = fmaf(p, y2, -4.944515323274145e-01f);
        p = fmaf(p, y2, 3.404879937665872e-01f);
        p = fmaf(p, y2, -2.741127028184656e-01f);
        p = fmaf(p, y2, 5.638259427386472e-01f);
    } else {
        p = -1.047766399936249e+01f;
        p = fmaf(p, y2, 1.297719955372516e+01f);
        p = fmaf(p, y2, -7.495518717768503e+00f);
        p = fmaf(p, y2, 2.921019019210786e+00f);
        p = fmaf(p, y2, -1.015265279202700e+00f);
        p = fmaf(p, y2, 4.218463358204948e-01f);
        p = fmaf(p, y2, -2.820767439740514e-01f);
        p = fmaf(p, y2, 5.641895067754075e-01f);
    }
    return z * q * p;
}

__device__ __forceinline__ float xla_ndtr32(float zf)
{
#pragma clang fp contract(off)
    const float c = __uint_as_float(0x3f3504f3u);   // f32(0.5*f32(sqrt(2)))
    const float w = zf * c;
    const float aw = fabsf(w);
    float y;
    if (aw < c) {
        y = 1.0f + xla_erf32(w);
    } else {
        const float e = (aw > 1.0f) ? xla_erfc_ge1(aw)
                                    : (1.0f - xla_erf32(aw));
        y = (w > 0.0f) ? (2.0f - e) : e;
    }
    return 0.5f * y;
}

// saturating f32->i16 cast (XLA semantics), then wrapping i16 add of l
__device__ __forceinline__ int quantize(float cdf, int l)
{
    int r = (int)rintf(cdf * 65280.0f);
    r = r > 32767 ? 32767 : r;          // XLA float->int16 saturates high
    r = r < -32768 ? -32768 : r;        // (unreachable here, r >= 0)
    return (int)((short)(r + l));       // int16 add wraps
}

// ===========================================================================
__global__ __launch_bounds__(256) void entropy_fused(
    const float* __restrict__ y,
    const float* __restrict__ W0, const float* __restrict__ b0,
    const float* __restrict__ W1, const float* __restrict__ b1,
    const float* __restrict__ W2, const float* __restrict__ b2,
    int* __restrict__ out)
{
#pragma clang fp contract(off)   // only explicit fmaf is fused

    __shared__ float tile[21][22];
    __shared__ float prm[9][257];   // [0..2]=mu  [3..5]=scale  [6..8]=softmax w

    const int bx  = blockIdx.x & 15;
    const int by  = blockIdx.x >> 4;
    const int tid = threadIdx.x;
    const int tx  = tid & 15;
    const int ty  = tid >> 4;

    for (int idx = tid; idx < 21 * 21; idx += 256) {
        const int r = idx / 21;
        const int c = idx - r * 21;
        int gy = by * 16 - 2 + r; gy = gy < 0 ? 0 : (gy > 255 ? 255 : gy);
        int gx = bx * 16 - 2 + c; gx = gx < 0 ? 0 : (gx > 255 ? 255 : gx);
        tile[r][c] = y[gy * 256 + gx];
    }
    __syncthreads();

    float patch[36];
#pragma unroll
    for (int i = 0; i < 6; ++i)
#pragma unroll
        for (int j = 0; j < 6; ++j)
            patch[i * 6 + j] = tile[ty + i][tx + j];

    for (int g = 0; g < 3; ++g) {
        float h0[64];
#pragma unroll 2
        for (int c = 0; c < 64; ++c) {
            float acc = 0.0f;
            const float* w = W0 + (g * 64 + c) * 36;
#pragma unroll
            for (int k = 0; k < 36; ++k)
                acc = fmaf(w[k], patch[k], acc);
            acc = acc + b0[g * 64 + c];
            h0[c] = fmaxf(acc, 0.0f);
        }

        float p0 = 0.0f, p1 = 0.0f, p2 = 0.0f;
#pragma unroll 2
        for (int c = 0; c < 64; ++c) {
            float acc = 0.0f;
            const float* w = W1 + (g * 64 + c) * 64;
#pragma unroll
            for (int j = 0; j < 64; ++j)
                acc = fmaf(w[j], h0[j], acc);
            acc = acc + b1[g * 64 + c];
            acc = fmaxf(acc, 0.0f);
            p0 = fmaf(W2[(3 * g + 0) * 64 + c], acc, p0);
            p1 = fmaf(W2[(3 * g + 1) * 64 + c], acc, p1);
            p2 = fmaf(W2[(3 * g + 2) * 64 + c], acc, p2);
        }
        p0 = p0 + b2[3 * g + 0];
        p1 = p1 + b2[3 * g + 1];
        p2 = p2 + b2[3 * g + 2];

        if (g == 0) {
            prm[0][tid] = p0; prm[1][tid] = p1; prm[2][tid] = p2;
        } else if (g == 1) {
            prm[3][tid] = fmaxf(xla_exp32(p0), 0.11f);
            prm[4][tid] = fmaxf(xla_exp32(p1), 0.11f);
            prm[5][tid] = fmaxf(xla_exp32(p2), 0.11f);
        } else {
            const float m  = fmaxf(fmaxf(p0, p1), p2);
            const float e0 = xla_exp32(p0 - m);
            const float e1 = xla_exp32(p1 - m);
            const float e2 = xla_exp32(p2 - m);
            const float s  = (e0 + e1) + e2;
            prm[6][tid] = e0 / s;
            prm[7][tid] = e1 / s;
            prm[8][tid] = e2 / s;
        }
    }
    __syncthreads();

    const int rowbase = (by * 16) * 256 + bx * 16;
    const float CLIP = (float)(1.0 - 1e-6);

    // phase 3a: point l = tid for every pixel p (coalesced stores)
    {
        const int l = tid;
        const float t32 = (l == 0)
            ? (float)(-147.5 / 255.0)
            : (float)((((double)l) - 127.5) / 255.0);
        for (int p = 0; p < 256; ++p) {
            const float mu0 = prm[0][p], mu1 = prm[1][p], mu2 = prm[2][p];
            const float sc0 = prm[3][p], sc1 = prm[4][p], sc2 = prm[5][p];
            const float w0  = prm[6][p], w1  = prm[7][p], w2  = prm[8][p];

            const float n0 = xla_ndtr32((t32 - mu0) / sc0);
            const float n1 = xla_ndtr32((t32 - mu1) / sc1);
            const float n2 = xla_ndtr32((t32 - mu2) / sc2);

            float cdf = fmaf(w2, n2, fmaf(w1, n1, w0 * n0));  // fused chain
            cdf = fminf(fmaxf(cdf, 0.0f), CLIP);

            const int pix = rowbase + (p >> 4) * 256 + (p & 15);
            out[(size_t)pix * LPTS + l] = quantize(cdf, l);
        }
    }

    // phase 3b: tail point l = 256, one pixel per thread
    {
        const int p = tid;
        const float t32 = (float)(148.5 / 255.0);
        const float mu0 = prm[0][p], mu1 = prm[1][p], mu2 = prm[2][p];
        const float sc0 = prm[3][p], sc1 = prm[4][p], sc2 = prm[5][p];
        const float w0  = prm[6][p], w1  = prm[7][p], w2  = prm[8][p];

        const float n0 = xla_ndtr32((t32 - mu0) / sc0);
        const float n1 = xla_ndtr32((t32 - mu1) / sc1);
        const float n2 = xla_ndtr32((t32 - mu2) / sc2);

        float cdf = fmaf(w2, n2, fmaf(w1, n1, w0 * n0));
        cdf = fminf(fmaxf(cdf, 0.0f), CLIP);

        const int pix = rowbase + (p >> 4) * 256 + (p & 15);
        out[(size_t)pix * LPTS + 256] = quantize(cdf, 256);
    }
}

extern "C" void kernel_launch(void* const* d_in, const int* in_sizes, int n_in,
                              void* d_out, int out_size, void* d_ws, size_t ws_size,
                              hipStream_t stream)
{
    const float* y  = (const float*)d_in[0];
    const float* W0 = (const float*)d_in[1];
    const float* b0 = (const float*)d_in[2];
    const float* W1 = (const float*)d_in[3];
    const float* b1 = (const float*)d_in[4];
    const float* W2 = (const float*)d_in[5];
    const float* b2 = (const float*)d_in[6];

    int* out = (int*)d_out;   // 65536 * 257 int32

    entropy_fused<<<dim3(256), dim3(256), 0, stream>>>(y, W0, b0, W1, b1, W2, b2, out);
}